// Round 1
// baseline (447.481 us; speedup 1.0000x reference)
//
#include <hip/hip_runtime.h>

#define QLEN 1024
#define PASTN 3072
#define KVLEN 4096
#define HIDN 4096
#define NHEAD 32
#define NKVH 8
#define HDIM 128
#define NQKVC 6144  // 4096 (Wq) + 1024 (Wk) + 1024 (Wv)

typedef unsigned short u16;
typedef __bf16 bf16x8 __attribute__((ext_vector_type(8)));
typedef float f32x4 __attribute__((ext_vector_type(4)));
typedef u16 us8 __attribute__((ext_vector_type(8)));

__device__ __forceinline__ u16 f2bf(float x) {
  unsigned u = __builtin_bit_cast(unsigned, x);
  u += 0x7fffu + ((u >> 16) & 1u);
  return (u16)(u >> 16);
}
__device__ __forceinline__ float bf2f(u16 b) {
  return __builtin_bit_cast(float, (unsigned)b << 16);
}

// async global->LDS, 16B per lane; LDS dest must be wave-uniform base (+lane*16)
#define GLL16(gp, lp) __builtin_amdgcn_global_load_lds( \
    (const __attribute__((address_space(1))) void*)(gp), \
    (__attribute__((address_space(3))) void*)(lp), 16, 0, 0)

// ---------------------------------------------------------------- convert
__global__ __launch_bounds__(256) void cvt_kernel(const float* __restrict__ src,
                                                  u16* __restrict__ dst, int n) {
  int i = (blockIdx.x * 256 + threadIdx.x) * 4;
  if (i >= n) return;
  float4 f = *(const float4*)(src + i);
  ushort4 o = make_ushort4(f2bf(f.x), f2bf(f.y), f2bf(f.z), f2bf(f.w));
  *(ushort4*)(dst + i) = o;
}

// ---------------------------------------------------------------- GEMM C = A * B^T
// A: [M][K] bf16 row-major, B: [N][K] bf16 row-major, C: [M][N] (f32 or bf16)
__device__ __forceinline__ void storeC(float* p, float v) { *p = v; }
__device__ __forceinline__ void storeC(u16* p, float v) { *p = f2bf(v); }

template <typename CT>
__global__ __launch_bounds__(256) void gemm_bt(const u16* __restrict__ A,
                                               const u16* __restrict__ B,
                                               CT* __restrict__ C, int M, int N, int K) {
  __shared__ u16 Alds[128 * 32];
  __shared__ u16 Blds[128 * 32];
  const int tid = threadIdx.x, wid = tid >> 6, lane = tid & 63;
  const int m0 = blockIdx.y * 128, n0 = blockIdx.x * 128;
  const int wm = (wid >> 1) * 64, wn = (wid & 1) * 64;
  const int l15 = lane & 15, l4 = lane >> 4;
  const int srow = lane >> 2, scol = (lane & 3) * 8;
  f32x4 acc[4][4] = {};
  for (int kt = 0; kt < K; kt += 32) {
    __syncthreads();
#pragma unroll
    for (int i = 0; i < 2; ++i) {
      int c = wid * 2 + i;
      GLL16(A + (size_t)(m0 + c * 16 + srow) * K + kt + scol, &Alds[c * 512]);
      GLL16(B + (size_t)(n0 + c * 16 + srow) * K + kt + scol, &Blds[c * 512]);
    }
    __syncthreads();
    bf16x8 a[4], b[4];
#pragma unroll
    for (int i = 0; i < 4; ++i) {
      a[i] = *(const bf16x8*)&Alds[(wm + i * 16 + l15) * 32 + l4 * 8];
      b[i] = *(const bf16x8*)&Blds[(wn + i * 16 + l15) * 32 + l4 * 8];
    }
#pragma unroll
    for (int i = 0; i < 4; ++i)
#pragma unroll
      for (int j = 0; j < 4; ++j)
        acc[i][j] = __builtin_amdgcn_mfma_f32_16x16x32_bf16(a[i], b[j], acc[i][j], 0, 0, 0);
  }
#pragma unroll
  for (int i = 0; i < 4; ++i)
#pragma unroll
    for (int j = 0; j < 4; ++j) {
      int row = m0 + wm + i * 16 + l4 * 4;
      int col = n0 + wn + j * 16 + l15;
#pragma unroll
      for (int r = 0; r < 4; ++r) storeC(&C[(size_t)(row + r) * N + col], acc[i][j][r]);
    }
}

// ---------------------------------------------------------------- RoPE on Q
// qkv: [1024][6144] bf16 (cols 0..4095 = Q). out: [1024][4096] bf16, roped.
__global__ __launch_bounds__(256) void rope_q_kernel(const u16* __restrict__ qkv,
                                                     u16* __restrict__ qr) {
  int idx = blockIdx.x * 256 + threadIdx.x;  // 1024*32*64
  int i = idx & 63, h = (idx >> 6) & 31, r = idx >> 11;
  float freq = __expf(-(float)i * (9.210340371976184f / 64.f));  // 10000^(-i/64)
  float angle = (float)(PASTN + r) * freq;
  float sn, cs;
  sincosf(angle, &sn, &cs);
  int base = r * NQKVC + h * HDIM + i;
  float x1 = bf2f(qkv[base]);
  float x2 = bf2f(qkv[base + 64]);
  int ob = r * HIDN + h * HDIM + i;
  qr[ob] = f2bf(x1 * cs - x2 * sn);
  qr[ob + 64] = f2bf(x2 * cs + x1 * sn);
}

// ---------------------------------------------------------------- K cache build
// out kb: [8][4096][128] bf16; rows <3072 from past_k (f32), rest roped new K.
__global__ __launch_bounds__(256) void repack_k_kernel(const float* __restrict__ past_k,
                                                       const u16* __restrict__ qkv,
                                                       u16* __restrict__ kb) {
  int idx = blockIdx.x * 256 + threadIdx.x;  // 8*4096*128
  int d = idx & 127, kv = (idx >> 7) & 4095, hk = idx >> 19;
  float val;
  if (kv < PASTN) {
    val = past_k[((size_t)hk * PASTN + kv) * HDIM + d];
  } else {
    int r = kv - PASTN;
    float x = bf2f(qkv[(size_t)r * NQKVC + 4096 + hk * HDIM + d]);
    float xp = bf2f(qkv[(size_t)r * NQKVC + 4096 + hk * HDIM + (d ^ 64)]);
    int i = d & 63;
    float freq = __expf(-(float)i * (9.210340371976184f / 64.f));
    float angle = (float)(PASTN + r) * freq;
    float sn, cs;
    sincosf(angle, &sn, &cs);
    val = (d < 64) ? (x * cs - xp * sn) : (x * cs + xp * sn);
  }
  kb[idx] = f2bf(val);
}

// ---------------------------------------------------------------- V^T cache build
// out vtb: [8][128][4096] bf16 (d-major so PV B-frags are contiguous along kv)
__global__ __launch_bounds__(256) void repack_vt_kernel(const float* __restrict__ past_v,
                                                        const u16* __restrict__ qkv,
                                                        u16* __restrict__ vtb) {
  __shared__ u16 tile[32][136];  // [kv][d], +8 pad
  int hk = blockIdx.y, kv0 = blockIdx.x * 32, tid = threadIdx.x;
  int j = tid >> 3, d0 = (tid & 7) * 16;
  if (kv0 < PASTN) {  // PASTN is a multiple of 32: tiles never straddle
    const float* src = past_v + ((size_t)hk * PASTN + kv0 + j) * HDIM + d0;
#pragma unroll
    for (int x = 0; x < 16; x += 4) {
      float4 f = *(const float4*)(src + x);
      tile[j][d0 + x] = f2bf(f.x);
      tile[j][d0 + x + 1] = f2bf(f.y);
      tile[j][d0 + x + 2] = f2bf(f.z);
      tile[j][d0 + x + 3] = f2bf(f.w);
    }
  } else {
    int r = kv0 - PASTN + j;
    const u16* src = qkv + (size_t)r * NQKVC + 5120 + hk * HDIM + d0;
    *(us8*)&tile[j][d0] = *(const us8*)src;
    *(us8*)&tile[j][d0 + 8] = *(const us8*)(src + 8);
  }
  __syncthreads();
  int d = tid >> 1, jb = (tid & 1) * 16;
  us8 o0, o1;
#pragma unroll
  for (int x = 0; x < 8; ++x) {
    o0[x] = tile[jb + x][d];
    o1[x] = tile[jb + 8 + x][d];
  }
  u16* dst = vtb + ((size_t)hk * HDIM + d) * KVLEN + kv0 + jb;
  *(us8*)dst = o0;
  *(us8*)(dst + 8) = o1;
}

// ---------------------------------------------------------------- flash attention
// q: [1024][4096] roped bf16; kb: [8][4096][128]; vtb: [8][128][4096]; o: [1024][4096]
__global__ __launch_bounds__(256) void attn_kernel(const u16* __restrict__ q,
                                                   const u16* __restrict__ kc,
                                                   const u16* __restrict__ vt,
                                                   u16* __restrict__ o) {
  __shared__ u16 Klds[64][136];      // [kv][d] +8 pad
  __shared__ u16 Vlds[128][72];      // [d][kv] +8 pad
  __shared__ u16 Plds[4][16][72];    // per-wave P relayout
  const int tid = threadIdx.x, wid = tid >> 6, lane = tid & 63;
  const int l15 = lane & 15, l4 = lane >> 4;
  const int h = blockIdx.y, hk = h >> 2;
  const int q0 = blockIdx.x * 64;
  bf16x8 qf[4];
  {
    const u16* qp = q + (size_t)(q0 + wid * 16 + l15) * HIDN + h * HDIM + l4 * 8;
#pragma unroll
    for (int dk = 0; dk < 4; ++dk) qf[dk] = *(const bf16x8*)(qp + dk * 32);
  }
  float m_run[4], l_run[4];
#pragma unroll
  for (int r = 0; r < 4; ++r) { m_run[r] = -1e30f; l_run[r] = 0.f; }
  f32x4 oacc[8] = {};
  const u16* kbase = kc + (size_t)hk * KVLEN * HDIM;
  const u16* vbase = vt + (size_t)hk * HDIM * KVLEN;
  const int ntiles = (PASTN + q0 + 64) >> 6;
  const float SCALE = 0.08838834764831845f;  // 1/sqrt(128)
  for (int t = 0; t < ntiles; ++t) {
    const int kv0 = t * 64;
    __syncthreads();
    {
      const int rr = tid >> 4, cc = (tid & 15) * 8;
#pragma unroll
      for (int p = 0; p < 4; ++p) {
        int row = p * 16 + rr;
        *(us8*)&Klds[row][cc] = *(const us8*)(kbase + (size_t)(kv0 + row) * HDIM + cc);
      }
      const int dd = tid >> 3, jj = (tid & 7) * 8;
#pragma unroll
      for (int p = 0; p < 4; ++p) {
        int d = p * 32 + dd;
        *(us8*)&Vlds[d][jj] = *(const us8*)(vbase + (size_t)d * KVLEN + kv0 + jj);
      }
    }
    __syncthreads();
    f32x4 s[4];
#pragma unroll
    for (int kj = 0; kj < 4; ++kj) {
      s[kj] = f32x4{0.f, 0.f, 0.f, 0.f};
#pragma unroll
      for (int dk = 0; dk < 4; ++dk) {
        bf16x8 kf = *(const bf16x8*)&Klds[kj * 16 + l15][dk * 32 + l4 * 8];
        s[kj] = __builtin_amdgcn_mfma_f32_16x16x32_bf16(qf[dk], kf, s[kj], 0, 0, 0);
      }
    }
    float pm[4] = {-1e30f, -1e30f, -1e30f, -1e30f};
    const bool maskt = (t == ntiles - 1);
#pragma unroll
    for (int kj = 0; kj < 4; ++kj)
#pragma unroll
      for (int r = 0; r < 4; ++r) {
        float v = s[kj][r] * SCALE;
        if (maskt) {
          int kpos = kv0 + kj * 16 + l15;
          int qpos = PASTN + q0 + wid * 16 + l4 * 4 + r;
          if (kpos > qpos) v = -1e30f;
        }
        s[kj][r] = v;
        pm[r] = fmaxf(pm[r], v);
      }
#pragma unroll
    for (int off = 1; off <= 8; off <<= 1)
#pragma unroll
      for (int r = 0; r < 4; ++r) pm[r] = fmaxf(pm[r], __shfl_xor(pm[r], off));
    float corr[4], rs[4];
#pragma unroll
    for (int r = 0; r < 4; ++r) {
      float mn = fmaxf(m_run[r], pm[r]);
      corr[r] = __expf(m_run[r] - mn);
      m_run[r] = mn;
      rs[r] = 0.f;
    }
#pragma unroll
    for (int kj = 0; kj < 4; ++kj)
#pragma unroll
      for (int r = 0; r < 4; ++r) {
        float p = __expf(s[kj][r] - m_run[r]);
        s[kj][r] = p;
        rs[r] += p;
      }
#pragma unroll
    for (int off = 1; off <= 8; off <<= 1)
#pragma unroll
      for (int r = 0; r < 4; ++r) rs[r] += __shfl_xor(rs[r], off);
#pragma unroll
    for (int r = 0; r < 4; ++r) l_run[r] = l_run[r] * corr[r] + rs[r];
#pragma unroll
    for (int di = 0; di < 8; ++di)
#pragma unroll
      for (int r = 0; r < 4; ++r) oacc[di][r] *= corr[r];
    // P (D-layout) -> per-wave LDS -> A-fragment layout
#pragma unroll
    for (int kj = 0; kj < 4; ++kj)
#pragma unroll
      for (int r = 0; r < 4; ++r)
        Plds[wid][l4 * 4 + r][kj * 16 + l15] = f2bf(s[kj][r]);
    asm volatile("s_waitcnt lgkmcnt(0)" ::: "memory");  // intra-wave ds_write->ds_read
    bf16x8 pa[2];
#pragma unroll
    for (int ks = 0; ks < 2; ++ks)
      pa[ks] = *(const bf16x8*)&Plds[wid][l15][ks * 32 + l4 * 8];
#pragma unroll
    for (int di = 0; di < 8; ++di)
#pragma unroll
      for (int ks = 0; ks < 2; ++ks) {
        bf16x8 vf = *(const bf16x8*)&Vlds[di * 16 + l15][ks * 32 + l4 * 8];
        oacc[di] = __builtin_amdgcn_mfma_f32_16x16x32_bf16(pa[ks], vf, oacc[di], 0, 0, 0);
      }
  }
  float inv[4];
#pragma unroll
  for (int r = 0; r < 4; ++r) inv[r] = 1.f / l_run[r];
#pragma unroll
  for (int di = 0; di < 8; ++di) {
    int row = q0 + wid * 16 + l4 * 4;
    int col = h * HDIM + di * 16 + l15;
#pragma unroll
    for (int r = 0; r < 4; ++r)
      o[(size_t)(row + r) * HIDN + col] = f2bf(oacc[di][r] * inv[r]);
  }
}

// ---------------------------------------------------------------- launch
extern "C" void kernel_launch(void* const* d_in, const int* in_sizes, int n_in,
                              void* d_out, int out_size, void* d_ws, size_t ws_size,
                              hipStream_t stream) {
  (void)in_sizes; (void)n_in; (void)out_size; (void)ws_size;
  const float* hidden = (const float*)d_in[0];
  // d_in[1] attention_mask: exactly causal-with-offset; implemented analytically.
  // d_in[2] position_ids: deterministic PAST+r; computed inline.
  const float* past_k = (const float*)d_in[3];
  const float* past_v = (const float*)d_in[4];
  const float* Wq = (const float*)d_in[5];
  const float* Wk = (const float*)d_in[6];
  const float* Wv = (const float*)d_in[7];
  const float* Wo = (const float*)d_in[8];
  float* out = (float*)d_out;

  // workspace carve-up (needs ~132 MB)
  char* w = (char*)d_ws;
  u16* hiddenb = (u16*)w; w += (size_t)QLEN * HIDN * 2;          // 8 MB
  u16* wqkv    = (u16*)w; w += (size_t)NQKVC * HIDN * 2;         // 48 MB
  u16* wo      = (u16*)w; w += (size_t)HIDN * HIDN * 2;          // 32 MB
  u16* qkvraw  = (u16*)w; w += (size_t)QLEN * NQKVC * 2;         // 12 MB
  u16* qrope   = (u16*)w; w += (size_t)QLEN * HIDN * 2;          // 8 MB
  u16* kbuf    = (u16*)w; w += (size_t)NKVH * KVLEN * HDIM * 2;  // 8 MB
  u16* vtbuf   = (u16*)w; w += (size_t)NKVH * HDIM * KVLEN * 2;  // 8 MB
  u16* attnb   = (u16*)w; w += (size_t)QLEN * HIDN * 2;          // 8 MB

  cvt_kernel<<<(QLEN * HIDN) / 1024, 256, 0, stream>>>(hidden, hiddenb, QLEN * HIDN);
  cvt_kernel<<<(NHEAD * HDIM * HIDN) / 1024, 256, 0, stream>>>(Wq, wqkv, NHEAD * HDIM * HIDN);
  cvt_kernel<<<(NKVH * HDIM * HIDN) / 1024, 256, 0, stream>>>(Wk, wqkv + (size_t)4096 * HIDN,
                                                              NKVH * HDIM * HIDN);
  cvt_kernel<<<(NKVH * HDIM * HIDN) / 1024, 256, 0, stream>>>(Wv, wqkv + (size_t)5120 * HIDN,
                                                              NKVH * HDIM * HIDN);
  cvt_kernel<<<(HIDN * HIDN) / 1024, 256, 0, stream>>>(Wo, wo, HIDN * HIDN);

  gemm_bt<u16><<<dim3(NQKVC / 128, QLEN / 128), 256, 0, stream>>>(hiddenb, wqkv, qkvraw,
                                                                  QLEN, NQKVC, HIDN);

  rope_q_kernel<<<(QLEN * NHEAD * 64) / 256, 256, 0, stream>>>(qkvraw, qrope);
  repack_k_kernel<<<(NKVH * KVLEN * HDIM) / 256, 256, 0, stream>>>(past_k, qkvraw, kbuf);
  repack_vt_kernel<<<dim3(KVLEN / 32, NKVH), 256, 0, stream>>>(past_v, qkvraw, vtbuf);

  attn_kernel<<<dim3(QLEN / 64, NHEAD), 256, 0, stream>>>(qrope, kbuf, vtbuf, attnb);

  gemm_bt<float><<<dim3(HIDN / 128, QLEN / 128), 256, 0, stream>>>(attnb, wo, out,
                                                                   QLEN, HIDN, HIDN);
}

// Round 2
// 391.393 us; speedup vs baseline: 1.1433x; 1.1433x over previous
//
#include <hip/hip_runtime.h>

#define QLEN 1024
#define PASTN 3072
#define KVLEN 4096
#define HIDN 4096
#define NHEAD 32
#define NKVH 8
#define HDIM 128
#define NQKVC 6144  // 4096 (Wq) + 1024 (Wk) + 1024 (Wv)

typedef unsigned short u16;
typedef __bf16 bf16x8 __attribute__((ext_vector_type(8)));
typedef float f32x4 __attribute__((ext_vector_type(4)));
typedef u16 us8 __attribute__((ext_vector_type(8)));

__device__ __forceinline__ u16 f2bf(float x) {
  unsigned u = __builtin_bit_cast(unsigned, x);
  u += 0x7fffu + ((u >> 16) & 1u);
  return (u16)(u >> 16);
}
__device__ __forceinline__ float bf2f(u16 b) {
  return __builtin_bit_cast(float, (unsigned)b << 16);
}

// async global->LDS, 16B per lane; LDS dest is wave-uniform base (+lane*16)
#define GLL16(gp, lp) __builtin_amdgcn_global_load_lds( \
    (const __attribute__((address_space(1))) void*)(gp), \
    (__attribute__((address_space(3))) void*)(lp), 16, 0, 0)

// ---------------------------------------------------------------- convert
__global__ __launch_bounds__(256) void cvt_kernel(const float* __restrict__ src,
                                                  u16* __restrict__ dst, int n) {
  int i = (blockIdx.x * 256 + threadIdx.x) * 4;
  if (i >= n) return;
  float4 f = *(const float4*)(src + i);
  ushort4 o = make_ushort4(f2bf(f.x), f2bf(f.y), f2bf(f.z), f2bf(f.w));
  *(ushort4*)(dst + i) = o;
}

// ---------------------------------------------------------------- GEMM C = A * B^T
__device__ __forceinline__ void storeC(float* p, float v) { *p = v; }
__device__ __forceinline__ void storeC(u16* p, float v) { *p = f2bf(v); }

template <typename CT>
__global__ __launch_bounds__(256) void gemm_bt(const u16* __restrict__ A,
                                               const u16* __restrict__ B,
                                               CT* __restrict__ C, int M, int N, int K) {
  __shared__ u16 Alds[128 * 32];
  __shared__ u16 Blds[128 * 32];
  const int tid = threadIdx.x, wid = tid >> 6, lane = tid & 63;
  const int m0 = blockIdx.y * 128, n0 = blockIdx.x * 128;
  const int wm = (wid >> 1) * 64, wn = (wid & 1) * 64;
  const int l15 = lane & 15, l4 = lane >> 4;
  const int srow = lane >> 2, scol = (lane & 3) * 8;
  f32x4 acc[4][4] = {};
  for (int kt = 0; kt < K; kt += 32) {
    __syncthreads();
#pragma unroll
    for (int i = 0; i < 2; ++i) {
      int c = wid * 2 + i;
      GLL16(A + (size_t)(m0 + c * 16 + srow) * K + kt + scol, &Alds[c * 512]);
      GLL16(B + (size_t)(n0 + c * 16 + srow) * K + kt + scol, &Blds[c * 512]);
    }
    __syncthreads();
    bf16x8 a[4], b[4];
#pragma unroll
    for (int i = 0; i < 4; ++i) {
      a[i] = *(const bf16x8*)&Alds[(wm + i * 16 + l15) * 32 + l4 * 8];
      b[i] = *(const bf16x8*)&Blds[(wn + i * 16 + l15) * 32 + l4 * 8];
    }
#pragma unroll
    for (int i = 0; i < 4; ++i)
#pragma unroll
      for (int j = 0; j < 4; ++j)
        acc[i][j] = __builtin_amdgcn_mfma_f32_16x16x32_bf16(a[i], b[j], acc[i][j], 0, 0, 0);
  }
#pragma unroll
  for (int i = 0; i < 4; ++i)
#pragma unroll
    for (int j = 0; j < 4; ++j) {
      int row = m0 + wm + i * 16 + l4 * 4;
      int col = n0 + wn + j * 16 + l15;
#pragma unroll
      for (int r = 0; r < 4; ++r) storeC(&C[(size_t)(row + r) * N + col], acc[i][j][r]);
    }
}

// ---------------------------------------------------------------- RoPE on Q
__global__ __launch_bounds__(256) void rope_q_kernel(const u16* __restrict__ qkv,
                                                     u16* __restrict__ qr) {
  int idx = blockIdx.x * 256 + threadIdx.x;  // 1024*32*64
  int i = idx & 63, h = (idx >> 6) & 31, r = idx >> 11;
  float freq = __expf(-(float)i * (9.210340371976184f / 64.f));
  float angle = (float)(PASTN + r) * freq;
  float sn, cs;
  sincosf(angle, &sn, &cs);
  int base = r * NQKVC + h * HDIM + i;
  float x1 = bf2f(qkv[base]);
  float x2 = bf2f(qkv[base + 64]);
  int ob = r * HIDN + h * HDIM + i;
  qr[ob] = f2bf(x1 * cs - x2 * sn);
  qr[ob + 64] = f2bf(x2 * cs + x1 * sn);
}

// ---------------------------------------------------------------- K cache build
__global__ __launch_bounds__(256) void repack_k_kernel(const float* __restrict__ past_k,
                                                       const u16* __restrict__ qkv,
                                                       u16* __restrict__ kb) {
  int idx = blockIdx.x * 256 + threadIdx.x;  // 8*4096*128
  int d = idx & 127, kv = (idx >> 7) & 4095, hk = idx >> 19;
  float val;
  if (kv < PASTN) {
    val = past_k[((size_t)hk * PASTN + kv) * HDIM + d];
  } else {
    int r = kv - PASTN;
    float x = bf2f(qkv[(size_t)r * NQKVC + 4096 + hk * HDIM + d]);
    float xp = bf2f(qkv[(size_t)r * NQKVC + 4096 + hk * HDIM + (d ^ 64)]);
    int i = d & 63;
    float freq = __expf(-(float)i * (9.210340371976184f / 64.f));
    float angle = (float)(PASTN + r) * freq;
    float sn, cs;
    sincosf(angle, &sn, &cs);
    val = (d < 64) ? (x * cs - xp * sn) : (x * cs + xp * sn);
  }
  kb[idx] = f2bf(val);
}

// ---------------------------------------------------------------- V^T cache build
__global__ __launch_bounds__(256) void repack_vt_kernel(const float* __restrict__ past_v,
                                                        const u16* __restrict__ qkv,
                                                        u16* __restrict__ vtb) {
  __shared__ u16 tile[32][136];
  int hk = blockIdx.y, kv0 = blockIdx.x * 32, tid = threadIdx.x;
  int j = tid >> 3, d0 = (tid & 7) * 16;
  if (kv0 < PASTN) {
    const float* src = past_v + ((size_t)hk * PASTN + kv0 + j) * HDIM + d0;
#pragma unroll
    for (int x = 0; x < 16; x += 4) {
      float4 f = *(const float4*)(src + x);
      tile[j][d0 + x] = f2bf(f.x);
      tile[j][d0 + x + 1] = f2bf(f.y);
      tile[j][d0 + x + 2] = f2bf(f.z);
      tile[j][d0 + x + 3] = f2bf(f.w);
    }
  } else {
    int r = kv0 - PASTN + j;
    const u16* src = qkv + (size_t)r * NQKVC + 5120 + hk * HDIM + d0;
    *(us8*)&tile[j][d0] = *(const us8*)src;
    *(us8*)&tile[j][d0 + 8] = *(const us8*)(src + 8);
  }
  __syncthreads();
  int d = tid >> 1, jb = (tid & 1) * 16;
  us8 o0, o1;
#pragma unroll
  for (int x = 0; x < 8; ++x) {
    o0[x] = tile[jb + x][d];
    o1[x] = tile[jb + 8 + x][d];
  }
  u16* dst = vtb + ((size_t)hk * HDIM + d) * KVLEN + kv0 + jb;
  *(us8*)dst = o0;
  *(us8*)(dst + 8) = o1;
}

// ---------------------------------------------------------------- flash attention
// Swapped-operand scheme: S^T = mfma(K, Q) so q = lane&15, keys in (l4, reg).
// K rows staged PERMUTED (physical row p holds global key kv0+kappa(p)) so the
// S^T registers are exactly the PV B-fragment: P never leaves registers.
// kappa(p) = (p>>5)*32 + ((p>>2)&3)*8 + ((p>>4)&1)*4 + (p&3).
// K/V LDS XOR-swizzled (byte ^= (row&7)<<4) with pre-swizzled global_load_lds src.
__global__ __launch_bounds__(256) void attn_kernel(const u16* __restrict__ q,
                                                   const u16* __restrict__ kc,
                                                   const u16* __restrict__ vt,
                                                   u16* __restrict__ o) {
  __shared__ u16 Klds[64 * 128];  // [row][d], swizzled, rows permuted by kappa
  __shared__ u16 Vlds[128 * 64];  // [d][kv], swizzled
  const int tid = threadIdx.x, wid = tid >> 6, lane = tid & 63;
  const int l15 = lane & 15, l4 = lane >> 4;
  const int h = blockIdx.y, hk = h >> 2;
  const int q0 = blockIdx.x * 64;
  // Q B-fragment: lane holds Q[q=q0+wid*16+l15][d = dk*32 + l4*8 + j]
  bf16x8 qf[4];
  {
    const u16* qp = q + (size_t)(q0 + wid * 16 + l15) * HIDN + h * HDIM + l4 * 8;
#pragma unroll
    for (int dk = 0; dk < 4; ++dk) qf[dk] = *(const bf16x8*)(qp + dk * 32);
  }
  float m_run = -1e30f, l_run = 0.f;
  f32x4 oacc[8] = {};
  const u16* kbase = kc + (size_t)hk * KVLEN * HDIM;
  const u16* vbase = vt + (size_t)hk * HDIM * KVLEN;
  const int ntiles = (PASTN + q0 + 64) >> 6;
  const float C = 0.12753102f;  // log2(e)/sqrt(128)
  const int qpos = PASTN + q0 + wid * 16 + l15;
  for (int t = 0; t < ntiles; ++t) {
    const int kv0 = t << 6;
    __syncthreads();
    // K stage: 4 GLL/wave; physical row -> global key kv0+kappa(row); cols pre-swizzled
#pragma unroll
    for (int i = 0; i < 4; ++i) {
      const int base = (wid * 4 + i) * 512;               // u16 units (1KB chunks)
      const int row = (wid * 4 + i) * 4 + l4;
      const int kap = (row & 0x23) | ((row & 0x0C) << 1) | ((row & 0x10) >> 2);
      const int col = l15 ^ (row & 7);                    // 16B chunk index
      GLL16(kbase + (size_t)(kv0 + kap) * HDIM + col * 8, &Klds[base]);
    }
    // V stage: 4 GLL/wave; [d][kv] rows, kv chunk pre-swizzled by d
#pragma unroll
    for (int i = 0; i < 4; ++i) {
      const int base = (wid * 4 + i) * 512;
      const int d = (wid * 4 + i) * 8 + (lane >> 3);
      const int kvo = ((lane & 7) ^ (d & 7)) * 8;
      GLL16(vbase + (size_t)d * KVLEN + kv0 + kvo, &Vlds[base]);
    }
    __syncthreads();
    // QK^T swapped: s[kj] reg r = score[key kv0+kappa(kj*16+l4*4+r)][q=l15]
    f32x4 s[4];
#pragma unroll
    for (int kj = 0; kj < 4; ++kj) {
      s[kj] = f32x4{0.f, 0.f, 0.f, 0.f};
#pragma unroll
      for (int dk = 0; dk < 4; ++dk) {
        const int idx = (kj * 16 + l15) * 128 + ((dk * 32 + l4 * 8) ^ ((l15 & 7) << 3));
        bf16x8 kf = *(const bf16x8*)&Klds[idx];
        s[kj] = __builtin_amdgcn_mfma_f32_16x16x32_bf16(kf, qf[dk], s[kj], 0, 0, 0);
      }
    }
    // scale to log2 domain, mask (last tile only), row max
    float pm = -1e30f;
    if (t == ntiles - 1) {
#pragma unroll
      for (int kj = 0; kj < 4; ++kj) {
        const int kb = kv0 + ((kj >> 1) << 5) + l4 * 8 + ((kj & 1) << 2);
#pragma unroll
        for (int r = 0; r < 4; ++r) {
          float v = s[kj][r] * C;
          if (kb + r > qpos) v = -1e30f;
          s[kj][r] = v;
          pm = fmaxf(pm, v);
        }
      }
    } else {
#pragma unroll
      for (int kj = 0; kj < 4; ++kj)
#pragma unroll
        for (int r = 0; r < 4; ++r) {
          float v = s[kj][r] * C;
          s[kj][r] = v;
          pm = fmaxf(pm, v);
        }
    }
    pm = fmaxf(pm, __shfl_xor(pm, 16));
    pm = fmaxf(pm, __shfl_xor(pm, 32));
    // rescale only when the running max actually grows (skip-rescale, T13@thr0)
    if (!__all(pm <= m_run)) {
      const float mn = fmaxf(m_run, pm);
      const float corr = exp2f(m_run - mn);
      m_run = mn;
      l_run *= corr;
#pragma unroll
      for (int di = 0; di < 8; ++di)
#pragma unroll
        for (int r = 0; r < 4; ++r) oacc[di][r] *= corr;
    }
    float rs = 0.f;
#pragma unroll
    for (int kj = 0; kj < 4; ++kj)
#pragma unroll
      for (int r = 0; r < 4; ++r) {
        const float p = exp2f(s[kj][r] - m_run);
        s[kj][r] = p;
        rs += p;
      }
    rs += __shfl_xor(rs, 16);
    rs += __shfl_xor(rs, 32);
    l_run += rs;
    // PV: P stays in registers as the B-fragment; V^T rows are the A-fragment
#pragma unroll
    for (int b = 0; b < 2; ++b) {
      bf16x8 pa;
#pragma unroll
      for (int r = 0; r < 4; ++r) {
        pa[r] = (__bf16)s[2 * b][r];
        pa[4 + r] = (__bf16)s[2 * b + 1][r];
      }
#pragma unroll
      for (int di = 0; di < 8; ++di) {
        const int d = di * 16 + l15;
        const int idx = d * 64 + ((b * 32 + l4 * 8) ^ ((d & 7) << 3));
        bf16x8 vf = *(const bf16x8*)&Vlds[idx];
        oacc[di] = __builtin_amdgcn_mfma_f32_16x16x32_bf16(vf, pa, oacc[di], 0, 0, 0);
      }
    }
  }
  // epilogue: O^T in regs (q=l15, d=di*16+l4*4+r) -> LDS transpose -> coalesced store
  const float inv = 1.f / l_run;
  __syncthreads();
#pragma unroll
  for (int di = 0; di < 8; ++di)
#pragma unroll
    for (int r = 0; r < 4; ++r)
      Klds[(wid * 16 + l15) * 128 + di * 16 + l4 * 4 + r] = f2bf(oacc[di][r] * inv);
  __syncthreads();
  {
    const int row = tid >> 2, c0 = (tid & 3) * 32;
    u16* dst = o + (size_t)(q0 + row) * HIDN + h * HDIM + c0;
    const u16* srcl = &Klds[row * 128 + c0];
#pragma unroll
    for (int x = 0; x < 4; ++x)
      *(us8*)(dst + x * 8) = *(const us8*)(srcl + x * 8);
  }
}

// ---------------------------------------------------------------- launch
extern "C" void kernel_launch(void* const* d_in, const int* in_sizes, int n_in,
                              void* d_out, int out_size, void* d_ws, size_t ws_size,
                              hipStream_t stream) {
  (void)in_sizes; (void)n_in; (void)out_size; (void)ws_size;
  const float* hidden = (const float*)d_in[0];
  const float* past_k = (const float*)d_in[3];
  const float* past_v = (const float*)d_in[4];
  const float* Wq = (const float*)d_in[5];
  const float* Wk = (const float*)d_in[6];
  const float* Wv = (const float*)d_in[7];
  const float* Wo = (const float*)d_in[8];
  float* out = (float*)d_out;

  char* w = (char*)d_ws;
  u16* hiddenb = (u16*)w; w += (size_t)QLEN * HIDN * 2;
  u16* wqkv    = (u16*)w; w += (size_t)NQKVC * HIDN * 2;
  u16* wo      = (u16*)w; w += (size_t)HIDN * HIDN * 2;
  u16* qkvraw  = (u16*)w; w += (size_t)QLEN * NQKVC * 2;
  u16* qrope   = (u16*)w; w += (size_t)QLEN * HIDN * 2;
  u16* kbuf    = (u16*)w; w += (size_t)NKVH * KVLEN * HDIM * 2;
  u16* vtbuf   = (u16*)w; w += (size_t)NKVH * HDIM * KVLEN * 2;
  u16* attnb   = (u16*)w; w += (size_t)QLEN * HIDN * 2;

  cvt_kernel<<<(QLEN * HIDN) / 1024, 256, 0, stream>>>(hidden, hiddenb, QLEN * HIDN);
  cvt_kernel<<<(NHEAD * HDIM * HIDN) / 1024, 256, 0, stream>>>(Wq, wqkv, NHEAD * HDIM * HIDN);
  cvt_kernel<<<(NKVH * HDIM * HIDN) / 1024, 256, 0, stream>>>(Wk, wqkv + (size_t)4096 * HIDN,
                                                              NKVH * HDIM * HIDN);
  cvt_kernel<<<(NKVH * HDIM * HIDN) / 1024, 256, 0, stream>>>(Wv, wqkv + (size_t)5120 * HIDN,
                                                              NKVH * HDIM * HIDN);
  cvt_kernel<<<(HIDN * HIDN) / 1024, 256, 0, stream>>>(Wo, wo, HIDN * HIDN);

  gemm_bt<u16><<<dim3(NQKVC / 128, QLEN / 128), 256, 0, stream>>>(hiddenb, wqkv, qkvraw,
                                                                  QLEN, NQKVC, HIDN);

  rope_q_kernel<<<(QLEN * NHEAD * 64) / 256, 256, 0, stream>>>(qkvraw, qrope);
  repack_k_kernel<<<(NKVH * KVLEN * HDIM) / 256, 256, 0, stream>>>(past_k, qkvraw, kbuf);
  repack_vt_kernel<<<dim3(KVLEN / 32, NKVH), 256, 0, stream>>>(past_v, qkvraw, vtbuf);

  attn_kernel<<<dim3(QLEN / 64, NHEAD), 256, 0, stream>>>(qrope, kbuf, vtbuf, attnb);

  gemm_bt<float><<<dim3(HIDN / 128, QLEN / 128), 256, 0, stream>>>(attnb, wo, out,
                                                                   QLEN, HIDN, HIDN);
}

// Round 3
// 375.576 us; speedup vs baseline: 1.1915x; 1.0421x over previous
//
#include <hip/hip_runtime.h>

#define QLEN 1024
#define PASTN 3072
#define KVLEN 4096
#define HIDN 4096
#define NHEAD 32
#define NKVH 8
#define HDIM 128
#define NQKVC 6144  // 4096 (Wq) + 1024 (Wk) + 1024 (Wv)

typedef unsigned short u16;
typedef __bf16 bf16x8 __attribute__((ext_vector_type(8)));
typedef float f32x4 __attribute__((ext_vector_type(4)));
typedef u16 us8 __attribute__((ext_vector_type(8)));
typedef u16 us4 __attribute__((ext_vector_type(4)));

__device__ __forceinline__ u16 f2bf(float x) {
  unsigned u = __builtin_bit_cast(unsigned, x);
  u += 0x7fffu + ((u >> 16) & 1u);
  return (u16)(u >> 16);
}
__device__ __forceinline__ float bf2f(u16 b) {
  return __builtin_bit_cast(float, (unsigned)b << 16);
}

// async global->LDS, 16B per lane; LDS dest is wave-uniform base (+lane*16)
#define GLL16(gp, lp) __builtin_amdgcn_global_load_lds( \
    (const __attribute__((address_space(1))) void*)(gp), \
    (__attribute__((address_space(3))) void*)(lp), 16, 0, 0)

// ---------------------------------------------------------------- convert
__global__ __launch_bounds__(256) void cvt_kernel(const float* __restrict__ src,
                                                  u16* __restrict__ dst, int n) {
  int i = (blockIdx.x * 256 + threadIdx.x) * 4;
  if (i >= n) return;
  float4 f = *(const float4*)(src + i);
  ushort4 o = make_ushort4(f2bf(f.x), f2bf(f.y), f2bf(f.z), f2bf(f.w));
  *(ushort4*)(dst + i) = o;
}

// ---------------------------------------------------------------- GEMM C = A * B^T
// Double-buffered LDS + prefetch: one __syncthreads per K-tile; the barrier's
// implicit vmcnt(0) drain is the wait for the NEXT tile's loads (issued before
// compute), so GLL latency hides under the 16 MFMAs.
__device__ __forceinline__ void storeC(float* p, float v) { *p = v; }
__device__ __forceinline__ void storeC(u16* p, float v) { *p = f2bf(v); }

template <typename CT>
__global__ __launch_bounds__(256) void gemm_bt(const u16* __restrict__ A,
                                               const u16* __restrict__ B,
                                               CT* __restrict__ C, int M, int N, int K) {
  __shared__ u16 Alds[2][128 * 32];
  __shared__ u16 Blds[2][128 * 32];
  const int tid = threadIdx.x, wid = tid >> 6, lane = tid & 63;
  const int m0 = blockIdx.y * 128, n0 = blockIdx.x * 128;
  const int wm = (wid >> 1) * 64, wn = (wid & 1) * 64;
  const int l15 = lane & 15, l4 = lane >> 4;
  const int srow = lane >> 2, scol = (lane & 3) * 8;
  f32x4 acc[4][4] = {};
  auto stage = [&](int buf, int kt) {
#pragma unroll
    for (int i = 0; i < 2; ++i) {
      int c = wid * 2 + i;
      GLL16(A + (size_t)(m0 + c * 16 + srow) * K + kt + scol, &Alds[buf][c * 512]);
      GLL16(B + (size_t)(n0 + c * 16 + srow) * K + kt + scol, &Blds[buf][c * 512]);
    }
  };
  stage(0, 0);
  __syncthreads();
  int cur = 0;
  for (int kt = 0; kt < K; kt += 32) {
    if (kt + 32 < K) stage(cur ^ 1, kt + 32);
    bf16x8 a[4], b[4];
#pragma unroll
    for (int i = 0; i < 4; ++i) {
      a[i] = *(const bf16x8*)&Alds[cur][(wm + i * 16 + l15) * 32 + l4 * 8];
      b[i] = *(const bf16x8*)&Blds[cur][(wn + i * 16 + l15) * 32 + l4 * 8];
    }
#pragma unroll
    for (int i = 0; i < 4; ++i)
#pragma unroll
      for (int j = 0; j < 4; ++j)
        acc[i][j] = __builtin_amdgcn_mfma_f32_16x16x32_bf16(a[i], b[j], acc[i][j], 0, 0, 0);
    __syncthreads();
    cur ^= 1;
  }
#pragma unroll
  for (int i = 0; i < 4; ++i)
#pragma unroll
    for (int j = 0; j < 4; ++j) {
      int row = m0 + wm + i * 16 + l4 * 4;
      int col = n0 + wn + j * 16 + l15;
#pragma unroll
      for (int r = 0; r < 4; ++r) storeC(&C[(size_t)(row + r) * N + col], acc[i][j][r]);
    }
}

// ---------------------------------------------------------------- RoPE on Q
__global__ __launch_bounds__(256) void rope_q_kernel(const u16* __restrict__ qkv,
                                                     u16* __restrict__ qr) {
  int idx = blockIdx.x * 256 + threadIdx.x;  // 1024*32*64
  int i = idx & 63, h = (idx >> 6) & 31, r = idx >> 11;
  float freq = __expf(-(float)i * (9.210340371976184f / 64.f));
  float angle = (float)(PASTN + r) * freq;
  float sn, cs;
  sincosf(angle, &sn, &cs);
  int base = r * NQKVC + h * HDIM + i;
  float x1 = bf2f(qkv[base]);
  float x2 = bf2f(qkv[base + 64]);
  int ob = r * HIDN + h * HDIM + i;
  qr[ob] = f2bf(x1 * cs - x2 * sn);
  qr[ob + 64] = f2bf(x2 * cs + x1 * sn);
}

// ---------------------------------------------------------------- K cache build
__global__ __launch_bounds__(256) void repack_k_kernel(const float* __restrict__ past_k,
                                                       const u16* __restrict__ qkv,
                                                       u16* __restrict__ kb) {
  int idx = blockIdx.x * 256 + threadIdx.x;  // 8*4096*128
  int d = idx & 127, kv = (idx >> 7) & 4095, hk = idx >> 19;
  float val;
  if (kv < PASTN) {
    val = past_k[((size_t)hk * PASTN + kv) * HDIM + d];
  } else {
    int r = kv - PASTN;
    float x = bf2f(qkv[(size_t)r * NQKVC + 4096 + hk * HDIM + d]);
    float xp = bf2f(qkv[(size_t)r * NQKVC + 4096 + hk * HDIM + (d ^ 64)]);
    int i = d & 63;
    float freq = __expf(-(float)i * (9.210340371976184f / 64.f));
    float angle = (float)(PASTN + r) * freq;
    float sn, cs;
    sincosf(angle, &sn, &cs);
    val = (d < 64) ? (x * cs - xp * sn) : (x * cs + xp * sn);
  }
  kb[idx] = f2bf(val);
}

// ---------------------------------------------------------------- V^T cache build
__global__ __launch_bounds__(256) void repack_vt_kernel(const float* __restrict__ past_v,
                                                        const u16* __restrict__ qkv,
                                                        u16* __restrict__ vtb) {
  __shared__ u16 tile[32][136];
  int hk = blockIdx.y, kv0 = blockIdx.x * 32, tid = threadIdx.x;
  int j = tid >> 3, d0 = (tid & 7) * 16;
  if (kv0 < PASTN) {
    const float* src = past_v + ((size_t)hk * PASTN + kv0 + j) * HDIM + d0;
#pragma unroll
    for (int x = 0; x < 16; x += 4) {
      float4 f = *(const float4*)(src + x);
      tile[j][d0 + x] = f2bf(f.x);
      tile[j][d0 + x + 1] = f2bf(f.y);
      tile[j][d0 + x + 2] = f2bf(f.z);
      tile[j][d0 + x + 3] = f2bf(f.w);
    }
  } else {
    int r = kv0 - PASTN + j;
    const u16* src = qkv + (size_t)r * NQKVC + 5120 + hk * HDIM + d0;
    *(us8*)&tile[j][d0] = *(const us8*)src;
    *(us8*)&tile[j][d0 + 8] = *(const us8*)(src + 8);
  }
  __syncthreads();
  int d = tid >> 1, jb = (tid & 1) * 16;
  us8 o0, o1;
#pragma unroll
  for (int x = 0; x < 8; ++x) {
    o0[x] = tile[jb + x][d];
    o1[x] = tile[jb + 8 + x][d];
  }
  u16* dst = vtb + ((size_t)hk * HDIM + d) * KVLEN + kv0 + jb;
  *(us8*)dst = o0;
  *(us8*)(dst + 8) = o1;
}

// ---------------------------------------------------------------- flash attention
// Swapped-operand scheme: S^T = mfma(K, Q); K rows staged permuted by kappa so
// S^T registers are exactly the PV B-fragment (P never leaves registers).
// Round 2: double-buffered K/V LDS with prefetch-before-compute — one
// __syncthreads per KV tile; GLL latency hides under QK+softmax+PV.
__global__ __launch_bounds__(256) void attn_kernel(const u16* __restrict__ q,
                                                   const u16* __restrict__ kc,
                                                   const u16* __restrict__ vt,
                                                   u16* __restrict__ o) {
  __shared__ u16 Klds[2][64 * 128];  // [row][d], swizzled, rows permuted by kappa
  __shared__ u16 Vlds[2][128 * 64];  // [d][kv], swizzled
  const int tid = threadIdx.x, wid = tid >> 6, lane = tid & 63;
  const int l15 = lane & 15, l4 = lane >> 4;
  const int h = blockIdx.y, hk = h >> 2;
  const int q0 = blockIdx.x * 64;
  bf16x8 qf[4];
  {
    const u16* qp = q + (size_t)(q0 + wid * 16 + l15) * HIDN + h * HDIM + l4 * 8;
#pragma unroll
    for (int dk = 0; dk < 4; ++dk) qf[dk] = *(const bf16x8*)(qp + dk * 32);
  }
  float m_run = -1e30f, l_run = 0.f;
  f32x4 oacc[8] = {};
  const u16* kbase = kc + (size_t)hk * KVLEN * HDIM;
  const u16* vbase = vt + (size_t)hk * HDIM * KVLEN;
  const int ntiles = (PASTN + q0 + 64) >> 6;
  const float C = 0.12753102f;  // log2(e)/sqrt(128)
  const int qpos = PASTN + q0 + wid * 16 + l15;
  auto stage = [&](int buf, int kv0) {
#pragma unroll
    for (int i = 0; i < 4; ++i) {
      const int base = (wid * 4 + i) * 512;
      const int row = (wid * 4 + i) * 4 + l4;
      const int kap = (row & 0x23) | ((row & 0x0C) << 1) | ((row & 0x10) >> 2);
      const int col = l15 ^ (row & 7);
      GLL16(kbase + (size_t)(kv0 + kap) * HDIM + col * 8, &Klds[buf][base]);
    }
#pragma unroll
    for (int i = 0; i < 4; ++i) {
      const int base = (wid * 4 + i) * 512;
      const int d = (wid * 4 + i) * 8 + (lane >> 3);
      const int kvo = ((lane & 7) ^ (d & 7)) * 8;
      GLL16(vbase + (size_t)d * KVLEN + kv0 + kvo, &Vlds[buf][base]);
    }
  };
  stage(0, 0);
  __syncthreads();
  int cur = 0;
  for (int t = 0; t < ntiles; ++t) {
    if (t + 1 < ntiles) stage(cur ^ 1, (t + 1) << 6);
    const int kv0 = t << 6;
    const u16* Kb = Klds[cur];
    const u16* Vb = Vlds[cur];
    // QK^T swapped: s[kj] reg r = score[key kv0+kappa(kj*16+l4*4+r)][q=l15]
    f32x4 s[4];
    __builtin_amdgcn_s_setprio(1);
#pragma unroll
    for (int kj = 0; kj < 4; ++kj) {
      s[kj] = f32x4{0.f, 0.f, 0.f, 0.f};
#pragma unroll
      for (int dk = 0; dk < 4; ++dk) {
        const int idx = (kj * 16 + l15) * 128 + ((dk * 32 + l4 * 8) ^ ((l15 & 7) << 3));
        bf16x8 kf = *(const bf16x8*)&Kb[idx];
        s[kj] = __builtin_amdgcn_mfma_f32_16x16x32_bf16(kf, qf[dk], s[kj], 0, 0, 0);
      }
    }
    __builtin_amdgcn_s_setprio(0);
    // scale to log2 domain, mask (last tile only), row max
    float pm = -1e30f;
    if (t == ntiles - 1) {
#pragma unroll
      for (int kj = 0; kj < 4; ++kj) {
        const int kb = kv0 + ((kj >> 1) << 5) + l4 * 8 + ((kj & 1) << 2);
#pragma unroll
        for (int r = 0; r < 4; ++r) {
          float v = s[kj][r] * C;
          if (kb + r > qpos) v = -1e30f;
          s[kj][r] = v;
          pm = fmaxf(pm, v);
        }
      }
    } else {
#pragma unroll
      for (int kj = 0; kj < 4; ++kj)
#pragma unroll
        for (int r = 0; r < 4; ++r) {
          float v = s[kj][r] * C;
          s[kj][r] = v;
          pm = fmaxf(pm, v);
        }
    }
    pm = fmaxf(pm, __shfl_xor(pm, 16));
    pm = fmaxf(pm, __shfl_xor(pm, 32));
    // rescale only when the running max actually grows (skip-rescale)
    if (!__all(pm <= m_run)) {
      const float mn = fmaxf(m_run, pm);
      const float corr = exp2f(m_run - mn);
      m_run = mn;
      l_run *= corr;
#pragma unroll
      for (int di = 0; di < 8; ++di)
#pragma unroll
        for (int r = 0; r < 4; ++r) oacc[di][r] *= corr;
    }
    float rs = 0.f;
#pragma unroll
    for (int kj = 0; kj < 4; ++kj)
#pragma unroll
      for (int r = 0; r < 4; ++r) {
        const float p = exp2f(s[kj][r] - m_run);
        s[kj][r] = p;
        rs += p;
      }
    rs += __shfl_xor(rs, 16);
    rs += __shfl_xor(rs, 32);
    l_run += rs;
    // PV: P stays in registers as the B-fragment; V^T rows are the A-fragment
    __builtin_amdgcn_s_setprio(1);
#pragma unroll
    for (int b = 0; b < 2; ++b) {
      bf16x8 pa;
#pragma unroll
      for (int r = 0; r < 4; ++r) {
        pa[r] = (__bf16)s[2 * b][r];
        pa[4 + r] = (__bf16)s[2 * b + 1][r];
      }
#pragma unroll
      for (int di = 0; di < 8; ++di) {
        const int d = di * 16 + l15;
        const int idx = d * 64 + ((b * 32 + l4 * 8) ^ ((d & 7) << 3));
        bf16x8 vf = *(const bf16x8*)&Vb[idx];
        oacc[di] = __builtin_amdgcn_mfma_f32_16x16x32_bf16(vf, pa, oacc[di], 0, 0, 0);
      }
    }
    __builtin_amdgcn_s_setprio(0);
    __syncthreads();
    cur ^= 1;
  }
  // epilogue: O^T (q=l15, d=di*16+l4*4+r) -> LDS transpose (swizzled) -> store
  const float inv = 1.f / l_run;
  u16* Kb0 = Klds[0];
#pragma unroll
  for (int di = 0; di < 8; ++di) {
    us4 w4;
#pragma unroll
    for (int r = 0; r < 4; ++r) w4[r] = f2bf(oacc[di][r] * inv);
    const int row = wid * 16 + l15;
    *(us4*)&Kb0[row * 128 + ((di * 16 + l4 * 4) ^ ((l15 & 7) << 3))] = w4;
  }
  __syncthreads();
  {
    const int row = tid >> 2, c0 = (tid & 3) * 32;
    u16* dst = o + (size_t)(q0 + row) * HIDN + h * HDIM + c0;
#pragma unroll
    for (int x = 0; x < 4; ++x)
      *(us8*)(dst + x * 8) =
          *(const us8*)&Kb0[row * 128 + ((c0 + x * 8) ^ ((row & 7) << 3))];
  }
}

// ---------------------------------------------------------------- launch
extern "C" void kernel_launch(void* const* d_in, const int* in_sizes, int n_in,
                              void* d_out, int out_size, void* d_ws, size_t ws_size,
                              hipStream_t stream) {
  (void)in_sizes; (void)n_in; (void)out_size; (void)ws_size;
  const float* hidden = (const float*)d_in[0];
  const float* past_k = (const float*)d_in[3];
  const float* past_v = (const float*)d_in[4];
  const float* Wq = (const float*)d_in[5];
  const float* Wk = (const float*)d_in[6];
  const float* Wv = (const float*)d_in[7];
  const float* Wo = (const float*)d_in[8];
  float* out = (float*)d_out;

  char* w = (char*)d_ws;
  u16* hiddenb = (u16*)w; w += (size_t)QLEN * HIDN * 2;
  u16* wqkv    = (u16*)w; w += (size_t)NQKVC * HIDN * 2;
  u16* wo      = (u16*)w; w += (size_t)HIDN * HIDN * 2;
  u16* qkvraw  = (u16*)w; w += (size_t)QLEN * NQKVC * 2;
  u16* qrope   = (u16*)w; w += (size_t)QLEN * HIDN * 2;
  u16* kbuf    = (u16*)w; w += (size_t)NKVH * KVLEN * HDIM * 2;
  u16* vtbuf   = (u16*)w; w += (size_t)NKVH * HDIM * KVLEN * 2;
  u16* attnb   = (u16*)w; w += (size_t)QLEN * HIDN * 2;

  cvt_kernel<<<(QLEN * HIDN) / 1024, 256, 0, stream>>>(hidden, hiddenb, QLEN * HIDN);
  cvt_kernel<<<(NHEAD * HDIM * HIDN) / 1024, 256, 0, stream>>>(Wq, wqkv, NHEAD * HDIM * HIDN);
  cvt_kernel<<<(NKVH * HDIM * HIDN) / 1024, 256, 0, stream>>>(Wk, wqkv + (size_t)4096 * HIDN,
                                                              NKVH * HDIM * HIDN);
  cvt_kernel<<<(NKVH * HDIM * HIDN) / 1024, 256, 0, stream>>>(Wv, wqkv + (size_t)5120 * HIDN,
                                                              NKVH * HDIM * HIDN);
  cvt_kernel<<<(HIDN * HIDN) / 1024, 256, 0, stream>>>(Wo, wo, HIDN * HIDN);

  gemm_bt<u16><<<dim3(NQKVC / 128, QLEN / 128), 256, 0, stream>>>(hiddenb, wqkv, qkvraw,
                                                                  QLEN, NQKVC, HIDN);

  rope_q_kernel<<<(QLEN * NHEAD * 64) / 256, 256, 0, stream>>>(qkvraw, qrope);
  repack_k_kernel<<<(NKVH * KVLEN * HDIM) / 256, 256, 0, stream>>>(past_k, qkvraw, kbuf);
  repack_vt_kernel<<<dim3(KVLEN / 32, NKVH), 256, 0, stream>>>(past_v, qkvraw, vtbuf);

  attn_kernel<<<dim3(QLEN / 64, NHEAD), 256, 0, stream>>>(qrope, kbuf, vtbuf, attnb);

  gemm_bt<float><<<dim3(HIDN / 128, QLEN / 128), 256, 0, stream>>>(attnb, wo, out,
                                                                   QLEN, HIDN, HIDN);
}